// Round 20
// baseline (87.130 us; speedup 1.0000x reference)
//
#include <hip/hip_runtime.h>
#include <hip/hip_bf16.h>

#define D_INc 256
#define D_KQc 512
#define D_Vc 64
#define NBb 8
#define Sc 1024
#define TDIMc 512
#define EPSV 1e-5f

typedef __bf16 bf16x8 __attribute__((ext_vector_type(8)));
typedef float f32x4 __attribute__((ext_vector_type(4)));

__device__ inline unsigned short f2bf(float f) {
    return __builtin_bit_cast(unsigned short, __float2bfloat16(f));
}
__device__ inline unsigned int pack2(float a, float b) {
    return (unsigned int)f2bf(a) | ((unsigned int)f2bf(b) << 16);
}
// Fast bf16 pair pack: round-half-up via +0x8000 bias, no NaN path.
__device__ inline unsigned int pack2f(float a, float b) {
    unsigned int ua = __builtin_bit_cast(unsigned int, a);
    unsigned int ub = __builtin_bit_cast(unsigned int, b);
    return ((ua + 0x8000u) >> 16) | ((ub + 0x8000u) & 0xffff0000u);
}
// Bare v_exp_f32 (2^x). Inputs bounded; no OCML fixup needed.
__device__ inline float fast_exp2(float x) {
    float r;
    asm("v_exp_f32 %0, %1" : "=v"(r) : "v"(x));
    return r;
}

// ---------------- K1: fused {temb+BN stats | weight prep} (verified) ----------------
__global__ __launch_bounds__(256) void k_pre(const float* __restrict__ x,
        const float* __restrict__ tin, const float* __restrict__ Wt,
        const float* __restrict__ bt, const float* __restrict__ gamma,
        const float* __restrict__ beta,
        const float* __restrict__ Wq, const float* __restrict__ Wk,
        const float* __restrict__ Wv, const float* __restrict__ Wp,
        float* __restrict__ aArr, float* __restrict__ offArr,
        __hip_bfloat16* __restrict__ wqfrag, __hip_bfloat16* __restrict__ wpfrag) {
    int blk = blockIdx.x, t = threadIdx.x;
    if (blk >= 256) {
        int b = blk - 256;
        if (b < 1088) {
            int j = b, c = t;
            float v;
            if (j < 512) v = Wq[c*D_KQc + j];
            else if (j < 1024) v = Wk[c*D_KQc + (j-512)];
            else v = Wv[c*D_Vc + (j-1024)];
            size_t fidx = (((size_t)(j>>4)*8 + (c>>5))*64 + ((j&15) + 16*((c&31)>>3)))*8 + (c&7);
            wqfrag[fidx] = __float2bfloat16(v);
        } else {
            int cout = b - 1088;
            for (int j = t; j < 512; j += 256) {
                int r = (j & 63)*8 + (j >> 6);
                float v = Wp[r*D_INc + cout];
                size_t fidx = (((size_t)(cout>>4)*16 + (j>>5))*64 + ((cout&15) + 16*((j&31)>>3)))*8 + (j&7);
                wpfrag[fidx] = __float2bfloat16(v);
            }
        }
        return;
    }
    int c = blk;
    __shared__ float wred[4];
    __shared__ float snA[NBb];
    __shared__ float tembL[NBb];
    {
        int n = t >> 5, j = t & 31;
        float p = 0.f;
        #pragma unroll
        for (int i2 = 0; i2 < 16; i2++) {
            int i = j*16 + i2;
            p += tin[n*TDIMc + i] * Wt[i*D_INc + c];
        }
        #pragma unroll
        for (int msk = 16; msk >= 1; msk >>= 1) p += __shfl_xor(p, msk);
        if (j == 0) tembL[n] = fmaxf(p + bt[c], 0.f);
    }
    __syncthreads();
    float sq = 0.f;
    for (int n = 0; n < NBb; n++) {
        const float4 v = reinterpret_cast<const float4*>(x + (size_t)(n*D_INc + c)*Sc)[t];
        float s = v.x + v.y + v.z + v.w;
        sq += v.x*v.x + v.y*v.y + v.z*v.z + v.w*v.w;
        for (int msk = 32; msk >= 1; msk >>= 1) s += __shfl_xor(s, msk);
        if ((t & 63) == 0) wred[t >> 6] = s;
        __syncthreads();
        if (t == 0) snA[n] = wred[0] + wred[1] + wred[2] + wred[3];
        __syncthreads();
    }
    for (int msk = 32; msk >= 1; msk >>= 1) sq += __shfl_xor(sq, msk);
    if ((t & 63) == 0) wred[t >> 6] = sq;
    __syncthreads();
    if (t == 0) {
        float sumsq = wred[0]+wred[1]+wred[2]+wred[3];
        float sumx = 0.f, tsum = 0.f, tsq = 0.f, cross = 0.f;
        for (int n = 0; n < NBb; n++) {
            float tv = tembL[n];
            sumx += snA[n]; tsum += tv; tsq += tv*tv; cross += tv*snA[n];
        }
        const float inv = 1.f / (float)(NBb * Sc);
        float mean = (sumx + (float)Sc * tsum) * inv;
        float ex2  = (sumsq + 2.f*cross + (float)Sc * tsq) * inv;
        float var  = ex2 - mean*mean;
        float a = gamma[c] * rsqrtf(var + EPSV);
        aArr[c] = a;
        float b = beta[c];
        for (int n = 0; n < NBb; n++)
            offArr[n*D_INc + c] = (tembL[n] - mean) * a + b;
    }
}

// ---------------- K4: afrag = BN(x) in QKV A-fragment order (verified) ----------------
__global__ __launch_bounds__(256) void k_xsb(const float* __restrict__ x,
        const float* __restrict__ aArr, const float* __restrict__ offArr,
        __hip_bfloat16* __restrict__ afrag) {
    __shared__ float tile[64][65];
    int s0 = blockIdx.x * 64, c0 = blockIdx.y * 64, n = blockIdx.z;
    int t = threadIdx.x;
    #pragma unroll
    for (int p = 0; p < 16; p++) {
        int idx = p*256 + t;
        int cl = idx >> 6, sl = idx & 63;
        int c = c0 + cl;
        tile[cl][sl] = x[((size_t)(n*D_INc + c))*Sc + s0 + sl] * aArr[c] + offArr[n*D_INc + c];
    }
    __syncthreads();
    #pragma unroll
    for (int p = 0; p < 16; p++) {
        int idx = p*256 + t;
        int sl = idx >> 6, cl = idx & 63;
        int s = s0 + sl, c = c0 + cl;
        size_t fidx = (((size_t)(n*64 + (s>>4))*8 + (c>>5))*64 + ((s&15) + 16*((c&31)>>3)))*8 + (c&7);
        afrag[fidx] = __float2bfloat16(tile[cl][sl]);
    }
}

// ---------------- K5: QKV bf16 MFMA (verified; K rows permuted for shfl-free PV) ----------------
__global__ __launch_bounds__(256) void k_qkvb(const __hip_bfloat16* __restrict__ afrag,
        const __hip_bfloat16* __restrict__ wqfrag, __hip_bfloat16* __restrict__ qfrag,
        __hip_bfloat16* __restrict__ kfrag, __hip_bfloat16* __restrict__ vfrag) {
    int jt = blockIdx.x, st = blockIdx.y, n = blockIdx.z;
    int t = threadIdx.x, w = t >> 6, l = t & 63;
    int lr = l & 15, lg = l >> 4;
    int s0 = st*64, j0 = jt*64;
    int sT = st*4 + w;
    const bf16x8* A = reinterpret_cast<const bf16x8*>(afrag + ((size_t)(n*64 + sT)*8)*512) + l;
    const bf16x8* B = reinterpret_cast<const bf16x8*>(wqfrag + ((size_t)(jt*4)*8)*512) + l;
    f32x4 acc[4] = {};
    for (int kk = 0; kk < 8; kk++) {
        bf16x8 a = A[kk*64];
        #pragma unroll
        for (int nt = 0; nt < 4; nt++) {
            bf16x8 b = B[(nt*8 + kk)*64];
            acc[nt] = __builtin_amdgcn_mfma_f32_16x16x32_bf16(a, b, acc[nt], 0, 0, 0);
        }
    }
    const float QSC = 0.044194173824159216f * 1.4426950408889634f; // scale * log2(e)
    #pragma unroll
    for (int nt = 0; nt < 4; nt++) {
        #pragma unroll
        for (int r = 0; r < 4; r++) {
            int s = s0 + w*16 + lg*4 + r;          // token index
            int j = j0 + nt*16 + lr;               // output-feature index
            float v = acc[nt][r];
            if (j0 < 512) {
                int h = j >> 6, d = j & 63;
                size_t idx = ((((size_t)(n*8 + h)*64 + (s>>4))*2 + (d>>5))*64
                              + ((s&15) + 16*((d&31)>>3)))*8 + (d&7);
                qfrag[idx] = __float2bfloat16(v * QSC);
            } else if (j0 < 1024) {
                int jk = j - 512;
                int h = jk >> 6, d = jk & 63;
                int sp = (s & ~31) + ((s>>2)&1)*16 + ((s&31)>>3)*4 + (s&3);
                size_t idx = ((((size_t)(n*8 + h)*64 + (sp>>4))*2 + (d>>5))*64
                              + ((sp&15) + 16*((d&31)>>3)))*8 + (d&7);
                kfrag[idx] = __float2bfloat16(v);
            } else {
                int dv = j - 1024;
                size_t idx = (((size_t)(n*32 + (s>>5))*4 + (dv>>4))*64
                              + ((dv&15) + 16*((s&31)>>3)))*8 + (s&7);
                vfrag[idx] = __float2bfloat16(v);
            }
        }
    }
}

// ---------------- K6: MFMA attention; 128-thread blocks (2 waves), grid 2048 ----------------
// Finer scheduling granularity: 8 blocks/CU residency possible (LDS 8.7KB), XCD pin kept.
__global__ __launch_bounds__(128) void k_attnb(const __hip_bfloat16* __restrict__ qfrag,
        const __hip_bfloat16* __restrict__ kfrag, const __hip_bfloat16* __restrict__ vfrag,
        __hip_bfloat16* __restrict__ obfrag) {
    __shared__ float olds[2][16][68];
    int bid = blockIdx.x;
    int h = bid & 7;
    int rest = bid >> 3;
    int qt = rest & 31;
    int n = rest >> 5;
    int t = threadIdx.x, w = t >> 6, l = t & 63;
    int lr = l & 15, lg = l >> 4;
    int qb2 = qt*2 + w;                    // 16-q block index 0..63
    const __hip_bfloat16* qbase = qfrag + (((size_t)(n*8 + h)*64 + qb2)*2)*512 + l*8;
    bf16x8 qf0 = *reinterpret_cast<const bf16x8*>(qbase);
    bf16x8 qf1 = *reinterpret_cast<const bf16x8*>(qbase + 512);
    const __hip_bfloat16* kf = kfrag + ((size_t)(n*8 + h)*64)*1024 + l*8;  // per kb16: 1024 elems
    const __hip_bfloat16* vf = vfrag + (size_t)n*32*2048 + l*8;            // per kb32: 2048 elems
    float lsum = 0.f;
    f32x4 oacc[4] = {};
    for (int kc = 0; kc < 16; kc++) {
        f32x4 sa[4] = {};
        #pragma unroll
        for (int g = 0; g < 4; g++) {
            const __hip_bfloat16* kr = kf + (size_t)(kc*4 + g)*1024;
            bf16x8 klo = *reinterpret_cast<const bf16x8*>(kr);
            bf16x8 khi = *reinterpret_cast<const bf16x8*>(kr + 512);
            sa[g] = __builtin_amdgcn_mfma_f32_16x16x32_bf16(klo, qf0, sa[g], 0,0,0);
            sa[g] = __builtin_amdgcn_mfma_f32_16x16x32_bf16(khi, qf1, sa[g], 0,0,0);
        }
        float p[16], gs[4];
        #pragma unroll
        for (int g = 0; g < 4; g++) {
            float e0 = fast_exp2(sa[g][0]);
            float e1 = fast_exp2(sa[g][1]);
            float e2 = fast_exp2(sa[g][2]);
            float e3 = fast_exp2(sa[g][3]);
            p[g*4+0] = e0; p[g*4+1] = e1; p[g*4+2] = e2; p[g*4+3] = e3;
            gs[g] = (e0 + e1) + (e2 + e3);
        }
        lsum += (gs[0] + gs[1]) + (gs[2] + gs[3]);
        #pragma unroll
        for (int half = 0; half < 2; half++) {
            uint4 pvu;
            pvu.x = pack2f(p[half*8+0], p[half*8+1]);
            pvu.y = pack2f(p[half*8+2], p[half*8+3]);
            pvu.z = pack2f(p[half*8+4], p[half*8+5]);
            pvu.w = pack2f(p[half*8+6], p[half*8+7]);
            bf16x8 pb = __builtin_bit_cast(bf16x8, pvu);
            const __hip_bfloat16* vblk = vf + (size_t)(kc*2 + half)*2048;
            #pragma unroll
            for (int mt = 0; mt < 4; mt++) {
                bf16x8 vfr = *reinterpret_cast<const bf16x8*>(vblk + mt*512);
                oacc[mt] = __builtin_amdgcn_mfma_f32_16x16x32_bf16(vfr, pb, oacc[mt], 0,0,0);
            }
        }
    }
    lsum += __shfl_xor(lsum, 16);
    lsum += __shfl_xor(lsum, 32);
    float inv = 1.f / lsum;
    #pragma unroll
    for (int mt = 0; mt < 4; mt++)
        #pragma unroll
        for (int r = 0; r < 4; r++)
            olds[w][lr][mt*16 + lg*4 + r] = oacc[mt][r] * inv;
    __syncthreads();
    // write proj-B fragments (verified epilogue; fast pack)
    #pragma unroll
    for (int half = 0; half < 2; half++) {
        const float* orow = &olds[w][l & 15][32*half + (l >> 4)*8];
        uint4 pk;
        pk.x = pack2f(orow[0], orow[1]);
        pk.y = pack2f(orow[2], orow[3]);
        pk.z = pack2f(orow[4], orow[5]);
        pk.w = pack2f(orow[6], orow[7]);
        *reinterpret_cast<uint4*>(obfrag
            + (((size_t)(n*64 + qb2)*16) + (h*2 + half))*512 + l*8) = pk;
    }
}

// ---------------- K7: proj MFMA (verified) ----------------
__global__ __launch_bounds__(256) void k_projb(const __hip_bfloat16* __restrict__ obfrag,
        const __hip_bfloat16* __restrict__ wpfrag, const float* __restrict__ bp,
        const float* __restrict__ x, float* __restrict__ out) {
    int st = blockIdx.x, ct = blockIdx.y, n = blockIdx.z;
    int t = threadIdx.x, w = t >> 6, l = t & 63;
    int lr = l & 15, lg = l >> 4;
    int s0 = st*64, c0 = ct*64 + w*16;
    int Ct = ct*4 + w;
    const bf16x8* A = reinterpret_cast<const bf16x8*>(wpfrag + ((size_t)Ct*16)*512) + l;
    const bf16x8* B = reinterpret_cast<const bf16x8*>(obfrag + ((size_t)(n*64 + st*4)*16)*512) + l;
    f32x4 acc[4] = {};
    for (int kk = 0; kk < 16; kk++) {
        bf16x8 a = A[kk*64];
        #pragma unroll
        for (int nt = 0; nt < 4; nt++) {
            bf16x8 b = B[(nt*16 + kk)*64];
            acc[nt] = __builtin_amdgcn_mfma_f32_16x16x32_bf16(a, b, acc[nt], 0,0,0);
        }
    }
    #pragma unroll
    for (int nt = 0; nt < 4; nt++) {
        #pragma unroll
        for (int r = 0; r < 4; r++) {
            int c = c0 + lg*4 + r;
            size_t idx = ((size_t)(n*D_INc + c))*Sc + s0 + nt*16 + lr;
            out[idx] = acc[nt][r] + bp[c] + x[idx];
        }
    }
}

extern "C" void kernel_launch(void* const* d_in, const int* in_sizes, int n_in,
                              void* d_out, int out_size, void* d_ws, size_t ws_size,
                              hipStream_t stream) {
    const float* x     = (const float*)d_in[0];
    const float* t     = (const float*)d_in[1];
    const float* Wt    = (const float*)d_in[2];
    const float* bt    = (const float*)d_in[3];
    const float* Wq    = (const float*)d_in[4];
    const float* Wk    = (const float*)d_in[5];
    const float* Wv    = (const float*)d_in[6];
    const float* Wp    = (const float*)d_in[7];
    const float* bp    = (const float*)d_in[8];
    const float* gamma = (const float*)d_in[9];
    const float* beta  = (const float*)d_in[10];
    char* ws = (char*)d_ws;
    float* aArr  = (float*)(ws + 8192);            // 1 KB
    float* offA  = (float*)(ws + 9216);            // 8 KB
    __hip_bfloat16* wqfrag = (__hip_bfloat16*)(ws + 32768);     // 544 KB
    __hip_bfloat16* wpfrag = (__hip_bfloat16*)(ws + 589824);    // 256 KB
    __hip_bfloat16* afrag  = (__hip_bfloat16*)(ws + 1048576);   // 4 MB
    __hip_bfloat16* qfrag  = (__hip_bfloat16*)(ws + 5242880);   // 8 MB
    __hip_bfloat16* kfrag  = (__hip_bfloat16*)(ws + 13631488);  // 8 MB
    __hip_bfloat16* vfrag  = (__hip_bfloat16*)(ws + 22020096);  // 1 MB
    __hip_bfloat16* obfrag = (__hip_bfloat16*)(ws + 23068672);  // 8 MB
    float* out = (float*)d_out;

    hipLaunchKernelGGL(k_pre,    dim3(1600),     dim3(256), 0, stream,
                       x, t, Wt, bt, gamma, beta, Wq, Wk, Wv, Wp,
                       aArr, offA, wqfrag, wpfrag);
    hipLaunchKernelGGL(k_xsb,    dim3(16,4,8),   dim3(256), 0, stream, x, aArr, offA, afrag);
    hipLaunchKernelGGL(k_qkvb,   dim3(17,16,8),  dim3(256), 0, stream, afrag, wqfrag, qfrag, kfrag, vfrag);
    hipLaunchKernelGGL(k_attnb,  dim3(2048),     dim3(128), 0, stream, qfrag, kfrag, vfrag, obfrag);
    hipLaunchKernelGGL(k_projb,  dim3(16,4,8),   dim3(256), 0, stream, obfrag, wpfrag, bp, x, out);
}

// Round 21
// 84.463 us; speedup vs baseline: 1.0316x; 1.0316x over previous
//
#include <hip/hip_runtime.h>
#include <hip/hip_bf16.h>

#define D_INc 256
#define D_KQc 512
#define D_Vc 64
#define NBb 8
#define Sc 1024
#define TDIMc 512
#define EPSV 1e-5f

typedef __bf16 bf16x8 __attribute__((ext_vector_type(8)));
typedef float f32x4 __attribute__((ext_vector_type(4)));

__device__ inline unsigned short f2bf(float f) {
    return __builtin_bit_cast(unsigned short, __float2bfloat16(f));
}
__device__ inline unsigned int pack2(float a, float b) {
    return (unsigned int)f2bf(a) | ((unsigned int)f2bf(b) << 16);
}
// Fast bf16 pair pack: round-half-up via +0x8000 bias, no NaN path.
__device__ inline unsigned int pack2f(float a, float b) {
    unsigned int ua = __builtin_bit_cast(unsigned int, a);
    unsigned int ub = __builtin_bit_cast(unsigned int, b);
    return ((ua + 0x8000u) >> 16) | ((ub + 0x8000u) & 0xffff0000u);
}
// Bare v_exp_f32 (2^x). Inputs bounded; no OCML fixup needed.
__device__ inline float fast_exp2(float x) {
    float r;
    asm("v_exp_f32 %0, %1" : "=v"(r) : "v"(x));
    return r;
}

// ---------------- K1: fused {temb+BN stats | weight prep} (verified) ----------------
__global__ __launch_bounds__(256) void k_pre(const float* __restrict__ x,
        const float* __restrict__ tin, const float* __restrict__ Wt,
        const float* __restrict__ bt, const float* __restrict__ gamma,
        const float* __restrict__ beta,
        const float* __restrict__ Wq, const float* __restrict__ Wk,
        const float* __restrict__ Wv, const float* __restrict__ Wp,
        float* __restrict__ aArr, float* __restrict__ offArr,
        __hip_bfloat16* __restrict__ wqfrag, __hip_bfloat16* __restrict__ wpfrag) {
    int blk = blockIdx.x, t = threadIdx.x;
    if (blk >= 256) {
        int b = blk - 256;
        if (b < 1088) {
            int j = b, c = t;
            float v;
            if (j < 512) v = Wq[c*D_KQc + j];
            else if (j < 1024) v = Wk[c*D_KQc + (j-512)];
            else v = Wv[c*D_Vc + (j-1024)];
            size_t fidx = (((size_t)(j>>4)*8 + (c>>5))*64 + ((j&15) + 16*((c&31)>>3)))*8 + (c&7);
            wqfrag[fidx] = __float2bfloat16(v);
        } else {
            int cout = b - 1088;
            for (int j = t; j < 512; j += 256) {
                int r = (j & 63)*8 + (j >> 6);
                float v = Wp[r*D_INc + cout];
                size_t fidx = (((size_t)(cout>>4)*16 + (j>>5))*64 + ((cout&15) + 16*((j&31)>>3)))*8 + (j&7);
                wpfrag[fidx] = __float2bfloat16(v);
            }
        }
        return;
    }
    int c = blk;
    __shared__ float wred[4];
    __shared__ float snA[NBb];
    __shared__ float tembL[NBb];
    {
        int n = t >> 5, j = t & 31;
        float p = 0.f;
        #pragma unroll
        for (int i2 = 0; i2 < 16; i2++) {
            int i = j*16 + i2;
            p += tin[n*TDIMc + i] * Wt[i*D_INc + c];
        }
        #pragma unroll
        for (int msk = 16; msk >= 1; msk >>= 1) p += __shfl_xor(p, msk);
        if (j == 0) tembL[n] = fmaxf(p + bt[c], 0.f);
    }
    __syncthreads();
    float sq = 0.f;
    for (int n = 0; n < NBb; n++) {
        const float4 v = reinterpret_cast<const float4*>(x + (size_t)(n*D_INc + c)*Sc)[t];
        float s = v.x + v.y + v.z + v.w;
        sq += v.x*v.x + v.y*v.y + v.z*v.z + v.w*v.w;
        for (int msk = 32; msk >= 1; msk >>= 1) s += __shfl_xor(s, msk);
        if ((t & 63) == 0) wred[t >> 6] = s;
        __syncthreads();
        if (t == 0) snA[n] = wred[0] + wred[1] + wred[2] + wred[3];
        __syncthreads();
    }
    for (int msk = 32; msk >= 1; msk >>= 1) sq += __shfl_xor(sq, msk);
    if ((t & 63) == 0) wred[t >> 6] = sq;
    __syncthreads();
    if (t == 0) {
        float sumsq = wred[0]+wred[1]+wred[2]+wred[3];
        float sumx = 0.f, tsum = 0.f, tsq = 0.f, cross = 0.f;
        for (int n = 0; n < NBb; n++) {
            float tv = tembL[n];
            sumx += snA[n]; tsum += tv; tsq += tv*tv; cross += tv*snA[n];
        }
        const float inv = 1.f / (float)(NBb * Sc);
        float mean = (sumx + (float)Sc * tsum) * inv;
        float ex2  = (sumsq + 2.f*cross + (float)Sc * tsq) * inv;
        float var  = ex2 - mean*mean;
        float a = gamma[c] * rsqrtf(var + EPSV);
        aArr[c] = a;
        float b = beta[c];
        for (int n = 0; n < NBb; n++)
            offArr[n*D_INc + c] = (tembL[n] - mean) * a + b;
    }
}

// ---------------- K4: afrag = BN(x) in QKV A-fragment order; vectorized uint4 stores ----------------
__global__ __launch_bounds__(256) void k_xsb(const float* __restrict__ x,
        const float* __restrict__ aArr, const float* __restrict__ offArr,
        __hip_bfloat16* __restrict__ afrag) {
    __shared__ float tile[64][65];
    int s0 = blockIdx.x * 64, c0 = blockIdx.y * 64, n = blockIdx.z;
    int t = threadIdx.x;
    #pragma unroll
    for (int p = 0; p < 16; p++) {
        int idx = p*256 + t;
        int cl = idx >> 6, sl = idx & 63;
        int c = c0 + cl;
        tile[cl][sl] = x[((size_t)(n*D_INc + c))*Sc + s0 + sl] * aArr[c] + offArr[n*D_INc + c];
    }
    __syncthreads();
    // 8 consecutive channels share one fragment slot (elem = c&7): write uint4.
    // m = (slhi*8 + cb)*16 + sllo; consecutive lanes -> consecutive 16B -> coalesced.
    #pragma unroll
    for (int p = 0; p < 2; p++) {
        int m = p*256 + t;
        int sllo = m & 15;
        int cb   = (m >> 4) & 7;
        int slhi = (m >> 7) & 3;
        int sl = slhi*16 + sllo;
        int s = s0 + sl;
        int cbase = c0 + cb*8;
        size_t frag = ((size_t)(n*64 + (s>>4)))*8 + (cbase>>5);
        int lane = (s & 15) + 16*((cbase & 31) >> 3);
        size_t base = (frag*64 + lane)*8;
        uint4 v;
        v.x = pack2(tile[cb*8+0][sl], tile[cb*8+1][sl]);
        v.y = pack2(tile[cb*8+2][sl], tile[cb*8+3][sl]);
        v.z = pack2(tile[cb*8+4][sl], tile[cb*8+5][sl]);
        v.w = pack2(tile[cb*8+6][sl], tile[cb*8+7][sl]);
        *reinterpret_cast<uint4*>(afrag + base) = v;
    }
}

// ---------------- K5: QKV bf16 MFMA (verified; K rows permuted for shfl-free PV) ----------------
__global__ __launch_bounds__(256) void k_qkvb(const __hip_bfloat16* __restrict__ afrag,
        const __hip_bfloat16* __restrict__ wqfrag, __hip_bfloat16* __restrict__ qfrag,
        __hip_bfloat16* __restrict__ kfrag, __hip_bfloat16* __restrict__ vfrag) {
    int jt = blockIdx.x, st = blockIdx.y, n = blockIdx.z;
    int t = threadIdx.x, w = t >> 6, l = t & 63;
    int lr = l & 15, lg = l >> 4;
    int s0 = st*64, j0 = jt*64;
    int sT = st*4 + w;
    const bf16x8* A = reinterpret_cast<const bf16x8*>(afrag + ((size_t)(n*64 + sT)*8)*512) + l;
    const bf16x8* B = reinterpret_cast<const bf16x8*>(wqfrag + ((size_t)(jt*4)*8)*512) + l;
    f32x4 acc[4] = {};
    for (int kk = 0; kk < 8; kk++) {
        bf16x8 a = A[kk*64];
        #pragma unroll
        for (int nt = 0; nt < 4; nt++) {
            bf16x8 b = B[(nt*8 + kk)*64];
            acc[nt] = __builtin_amdgcn_mfma_f32_16x16x32_bf16(a, b, acc[nt], 0, 0, 0);
        }
    }
    const float QSC = 0.044194173824159216f * 1.4426950408889634f; // scale * log2(e)
    #pragma unroll
    for (int nt = 0; nt < 4; nt++) {
        #pragma unroll
        for (int r = 0; r < 4; r++) {
            int s = s0 + w*16 + lg*4 + r;          // token index
            int j = j0 + nt*16 + lr;               // output-feature index
            float v = acc[nt][r];
            if (j0 < 512) {
                int h = j >> 6, d = j & 63;
                size_t idx = ((((size_t)(n*8 + h)*64 + (s>>4))*2 + (d>>5))*64
                              + ((s&15) + 16*((d&31)>>3)))*8 + (d&7);
                qfrag[idx] = __float2bfloat16(v * QSC);
            } else if (j0 < 1024) {
                int jk = j - 512;
                int h = jk >> 6, d = jk & 63;
                int sp = (s & ~31) + ((s>>2)&1)*16 + ((s&31)>>3)*4 + (s&3);
                size_t idx = ((((size_t)(n*8 + h)*64 + (sp>>4))*2 + (d>>5))*64
                              + ((sp&15) + 16*((d&31)>>3)))*8 + (d&7);
                kfrag[idx] = __float2bfloat16(v);
            } else {
                int dv = j - 1024;
                size_t idx = (((size_t)(n*32 + (s>>5))*4 + (dv>>4))*64
                              + ((dv&15) + 16*((s&31)>>3)))*8 + (s&7);
                vfrag[idx] = __float2bfloat16(v);
            }
        }
    }
}

// ---------------- K6: MFMA attention (best-measured R18 config: 256 thr, grid 1024) ----------------
__global__ __launch_bounds__(256) void k_attnb(const __hip_bfloat16* __restrict__ qfrag,
        const __hip_bfloat16* __restrict__ kfrag, const __hip_bfloat16* __restrict__ vfrag,
        __hip_bfloat16* __restrict__ obfrag) {
    __shared__ float olds[4][16][68];
    int bid = blockIdx.x;
    int h = bid & 7;
    int rest = bid >> 3;
    int qt = rest & 15;
    int n = rest >> 4;
    int t = threadIdx.x, w = t >> 6, l = t & 63;
    int lr = l & 15, lg = l >> 4;
    int qb2 = qt*4 + w;                    // 16-q block index 0..63
    const __hip_bfloat16* qbase = qfrag + (((size_t)(n*8 + h)*64 + qb2)*2)*512 + l*8;
    bf16x8 qf0 = *reinterpret_cast<const bf16x8*>(qbase);
    bf16x8 qf1 = *reinterpret_cast<const bf16x8*>(qbase + 512);
    const __hip_bfloat16* kf = kfrag + ((size_t)(n*8 + h)*64)*1024 + l*8;  // per kb16: 1024 elems
    const __hip_bfloat16* vf = vfrag + (size_t)n*32*2048 + l*8;            // per kb32: 2048 elems
    float lsum = 0.f;
    f32x4 oacc[4] = {};
    for (int kc = 0; kc < 16; kc++) {
        f32x4 sa[4] = {};
        #pragma unroll
        for (int g = 0; g < 4; g++) {
            const __hip_bfloat16* kr = kf + (size_t)(kc*4 + g)*1024;
            bf16x8 klo = *reinterpret_cast<const bf16x8*>(kr);
            bf16x8 khi = *reinterpret_cast<const bf16x8*>(kr + 512);
            sa[g] = __builtin_amdgcn_mfma_f32_16x16x32_bf16(klo, qf0, sa[g], 0,0,0);
            sa[g] = __builtin_amdgcn_mfma_f32_16x16x32_bf16(khi, qf1, sa[g], 0,0,0);
        }
        float p[16], gs[4];
        #pragma unroll
        for (int g = 0; g < 4; g++) {
            float e0 = fast_exp2(sa[g][0]);
            float e1 = fast_exp2(sa[g][1]);
            float e2 = fast_exp2(sa[g][2]);
            float e3 = fast_exp2(sa[g][3]);
            p[g*4+0] = e0; p[g*4+1] = e1; p[g*4+2] = e2; p[g*4+3] = e3;
            gs[g] = (e0 + e1) + (e2 + e3);
        }
        lsum += (gs[0] + gs[1]) + (gs[2] + gs[3]);
        #pragma unroll
        for (int half = 0; half < 2; half++) {
            uint4 pvu;
            pvu.x = pack2f(p[half*8+0], p[half*8+1]);
            pvu.y = pack2f(p[half*8+2], p[half*8+3]);
            pvu.z = pack2f(p[half*8+4], p[half*8+5]);
            pvu.w = pack2f(p[half*8+6], p[half*8+7]);
            bf16x8 pb = __builtin_bit_cast(bf16x8, pvu);
            const __hip_bfloat16* vblk = vf + (size_t)(kc*2 + half)*2048;
            #pragma unroll
            for (int mt = 0; mt < 4; mt++) {
                bf16x8 vfr = *reinterpret_cast<const bf16x8*>(vblk + mt*512);
                oacc[mt] = __builtin_amdgcn_mfma_f32_16x16x32_bf16(vfr, pb, oacc[mt], 0,0,0);
            }
        }
    }
    lsum += __shfl_xor(lsum, 16);
    lsum += __shfl_xor(lsum, 32);
    float inv = 1.f / lsum;
    #pragma unroll
    for (int mt = 0; mt < 4; mt++)
        #pragma unroll
        for (int r = 0; r < 4; r++)
            olds[w][lr][mt*16 + lg*4 + r] = oacc[mt][r] * inv;
    __syncthreads();
    // write proj-B fragments (verified epilogue; fast pack)
    #pragma unroll
    for (int half = 0; half < 2; half++) {
        const float* orow = &olds[w][l & 15][32*half + (l >> 4)*8];
        uint4 pk;
        pk.x = pack2f(orow[0], orow[1]);
        pk.y = pack2f(orow[2], orow[3]);
        pk.z = pack2f(orow[4], orow[5]);
        pk.w = pack2f(orow[6], orow[7]);
        *reinterpret_cast<uint4*>(obfrag
            + (((size_t)(n*64 + qb2)*16) + (h*2 + half))*512 + l*8) = pk;
    }
}

// ---------------- K7: proj MFMA (verified) ----------------
__global__ __launch_bounds__(256) void k_projb(const __hip_bfloat16* __restrict__ obfrag,
        const __hip_bfloat16* __restrict__ wpfrag, const float* __restrict__ bp,
        const float* __restrict__ x, float* __restrict__ out) {
    int st = blockIdx.x, ct = blockIdx.y, n = blockIdx.z;
    int t = threadIdx.x, w = t >> 6, l = t & 63;
    int lr = l & 15, lg = l >> 4;
    int s0 = st*64, c0 = ct*64 + w*16;
    int Ct = ct*4 + w;
    const bf16x8* A = reinterpret_cast<const bf16x8*>(wpfrag + ((size_t)Ct*16)*512) + l;
    const bf16x8* B = reinterpret_cast<const bf16x8*>(obfrag + ((size_t)(n*64 + st*4)*16)*512) + l;
    f32x4 acc[4] = {};
    for (int kk = 0; kk < 16; kk++) {
        bf16x8 a = A[kk*64];
        #pragma unroll
        for (int nt = 0; nt < 4; nt++) {
            bf16x8 b = B[(nt*16 + kk)*64];
            acc[nt] = __builtin_amdgcn_mfma_f32_16x16x32_bf16(a, b, acc[nt], 0,0,0);
        }
    }
    #pragma unroll
    for (int nt = 0; nt < 4; nt++) {
        #pragma unroll
        for (int r = 0; r < 4; r++) {
            int c = c0 + lg*4 + r;
            size_t idx = ((size_t)(n*D_INc + c))*Sc + s0 + nt*16 + lr;
            out[idx] = acc[nt][r] + bp[c] + x[idx];
        }
    }
}

extern "C" void kernel_launch(void* const* d_in, const int* in_sizes, int n_in,
                              void* d_out, int out_size, void* d_ws, size_t ws_size,
                              hipStream_t stream) {
    const float* x     = (const float*)d_in[0];
    const float* t     = (const float*)d_in[1];
    const float* Wt    = (const float*)d_in[2];
    const float* bt    = (const float*)d_in[3];
    const float* Wq    = (const float*)d_in[4];
    const float* Wk    = (const float*)d_in[5];
    const float* Wv    = (const float*)d_in[6];
    const float* Wp    = (const float*)d_in[7];
    const float* bp    = (const float*)d_in[8];
    const float* gamma = (const float*)d_in[9];
    const float* beta  = (const float*)d_in[10];
    char* ws = (char*)d_ws;
    float* aArr  = (float*)(ws + 8192);            // 1 KB
    float* offA  = (float*)(ws + 9216);            // 8 KB
    __hip_bfloat16* wqfrag = (__hip_bfloat16*)(ws + 32768);     // 544 KB
    __hip_bfloat16* wpfrag = (__hip_bfloat16*)(ws + 589824);    // 256 KB
    __hip_bfloat16* afrag  = (__hip_bfloat16*)(ws + 1048576);   // 4 MB
    __hip_bfloat16* qfrag  = (__hip_bfloat16*)(ws + 5242880);   // 8 MB
    __hip_bfloat16* kfrag  = (__hip_bfloat16*)(ws + 13631488);  // 8 MB
    __hip_bfloat16* vfrag  = (__hip_bfloat16*)(ws + 22020096);  // 1 MB
    __hip_bfloat16* obfrag = (__hip_bfloat16*)(ws + 23068672);  // 8 MB
    float* out = (float*)d_out;

    hipLaunchKernelGGL(k_pre,    dim3(1600),     dim3(256), 0, stream,
                       x, t, Wt, bt, gamma, beta, Wq, Wk, Wv, Wp,
                       aArr, offA, wqfrag, wpfrag);
    hipLaunchKernelGGL(k_xsb,    dim3(16,4,8),   dim3(256), 0, stream, x, aArr, offA, afrag);
    hipLaunchKernelGGL(k_qkvb,   dim3(17,16,8),  dim3(256), 0, stream, afrag, wqfrag, qfrag, kfrag, vfrag);
    hipLaunchKernelGGL(k_attnb,  dim3(1024),     dim3(256), 0, stream, qfrag, kfrag, vfrag, obfrag);
    hipLaunchKernelGGL(k_projb,  dim3(16,4,8),   dim3(256), 0, stream, obfrag, wpfrag, bp, x, out);
}